// Round 1
// baseline (636.986 us; speedup 1.0000x reference)
//
#include <hip/hip_runtime.h>

// Problem constants (fixed by setup_inputs)
constexpr int Bn = 128, Cn = 3, Sn = 256;
constexpr int HWn = Sn * Sn;          // 65536
constexpr int NSYS = Bn * Cn * Sn;    // 98304 systems per sweep
constexpr float DTf = 0.05f;
constexpr float EPSf = 1e-6f;
constexpr float MAXCf = 1.0f;

// ws float layout:
//   [0..5]                 spatial means: alpha(3), beta(3)
//   [8..25]                r[step][dir][c]  (18)
//   [32 .. 32+4608)        cp tables   [18][256]
//   [4640 .. 4640+4608)    dinv tables [18][256]
#define WS_R    8
#define WS_CP   32
#define WS_DINV 4640

__global__ void means_kernel(const float* __restrict__ aspat,
                             const float* __restrict__ bspat,
                             float* __restrict__ ws) {
  int which = blockIdx.x / 3, c = blockIdx.x % 3;
  const float* src = (which == 0 ? aspat : bspat) + c * HWn;
  double acc = 0.0;
  for (int i = threadIdx.x; i < HWn; i += 256) acc += (double)src[i];
  __shared__ double sm[256];
  sm[threadIdx.x] = acc;
  __syncthreads();
  for (int s = 128; s > 0; s >>= 1) {
    if (threadIdx.x < s) sm[threadIdx.x] += sm[threadIdx.x + s];
    __syncthreads();
  }
  if (threadIdx.x == 0) ws[which * 3 + c] = (float)(sm[0] * (1.0 / HWn));
}

// One thread per (step, dir, channel): build cp[256], dinv[256], r.
__global__ void coeff_kernel(const float* __restrict__ alpha_base,
                             const float* __restrict__ beta_base,
                             float* __restrict__ ws) {
  int id = threadIdx.x;
  if (id >= 18) return;
  int s = id / 6, dir = (id / 3) % 2, c = id % 3;
  float t = (float)s * DTf;
  float mean = ws[dir * 3 + c];
  float base = (dir == 0) ? alpha_base[c] : beta_base[c];
  float coef = fminf(fmaxf(base + mean * t, EPSf), MAXCf);
  float r = coef * (DTf * 0.5f);  // DX = 1
  ws[WS_R + id] = r;
  float* cp = ws + WS_CP + id * 256;
  float* dinv = ws + WS_DINV + id * 256;
  float b0 = 1.0f + r;
  float bi = 1.0f + 2.0f * r;
  dinv[0] = 1.0f / (b0 + EPSf);
  cp[0] = -r / (b0 + EPSf);
  for (int i = 1; i < 256; ++i) {
    float b = (i == 255) ? b0 : bi;
    float denom = fmaxf(b + r * cp[i - 1], EPSf);  // b - a*cp_prev, a=-r
    cp[i] = -r / denom;
    dinv[i] = 1.0f / denom;
  }
  cp[255] = 0.0f;  // unused by back-substitution (matches reference)
}

// X sweep: systems along W (contiguous). One thread per (b,c,h).
// Forward writes dp into dst, backward rewrites dst in place (same thread).
// NOTE: src may alias dst (steps > 0) — per-element read-then-write by the
// owning thread only, so no __restrict__ on src/dst.
__global__ void sweep_x(const float* src, float* dst,
                        const float* __restrict__ ws, int step) {
  __shared__ float s_cp[3][256], s_dinv[3][256], s_r[3];
  int tid = threadIdx.x;
  for (int i = tid; i < 3 * 256; i += 256) {
    int c = i >> 8, w = i & 255;
    int id = step * 6 + c;  // dir = 0
    s_cp[c][w] = ws[WS_CP + id * 256 + w];
    s_dinv[c][w] = ws[WS_DINV + id * 256 + w];
  }
  if (tid < 3) s_r[tid] = ws[WS_R + step * 6 + tid];
  __syncthreads();

  int g = blockIdx.x * 256 + tid;          // (b*C + c)*256 + h
  int c = (g >> 8) % 3;
  float r = s_r[c];
  const float* cp = s_cp[c];
  const float* dinv = s_dinv[c];
  const float4* sp = (const float4*)(src + (size_t)g * 256);
  float4* dq = (float4*)(dst + (size_t)g * 256);

  // forward: dp
  float prev;
  {
    float4 v = sp[0];
    float d0 = v.x * dinv[0];
    float d1 = (v.y + r * d0) * dinv[1];
    float d2 = (v.z + r * d1) * dinv[2];
    float d3 = (v.w + r * d2) * dinv[3];
    dq[0] = make_float4(d0, d1, d2, d3);
    prev = d3;
  }
  for (int q = 1; q < 64; ++q) {
    float4 v = sp[q];
    int w = q * 4;
    float d0 = (v.x + r * prev) * dinv[w];
    float d1 = (v.y + r * d0) * dinv[w + 1];
    float d2 = (v.z + r * d1) * dinv[w + 2];
    float d3 = (v.w + r * d2) * dinv[w + 3];
    dq[q] = make_float4(d0, d1, d2, d3);
    prev = d3;
  }
  // backward: x
  float x;
  {
    float4 v = dq[63];
    float x3 = v.w;
    float x2 = v.z - cp[254] * x3;
    float x1 = v.y - cp[253] * x2;
    float x0 = v.x - cp[252] * x1;
    dq[63] = make_float4(x0, x1, x2, x3);
    x = x0;
  }
  for (int q = 62; q >= 0; --q) {
    float4 v = dq[q];
    int w = q * 4;
    float x3 = v.w - cp[w + 3] * x;
    float x2 = v.z - cp[w + 2] * x3;
    float x1 = v.y - cp[w + 1] * x2;
    float x0 = v.x - cp[w] * x1;
    dq[q] = make_float4(x0, x1, x2, x3);
    x = x0;
  }
}

// Y sweep: systems along H (stride 256). One thread per (b,c,w) — coalesced.
// In place on buf; final write scaled by diag(coupling)[c].
__global__ void sweep_y(float* buf, const float* __restrict__ ws,
                        const float* __restrict__ coupling, int step) {
  __shared__ float s_cp[3][256], s_dinv[3][256], s_r[3], s_diag[3];
  int tid = threadIdx.x;
  for (int i = tid; i < 3 * 256; i += 256) {
    int c = i >> 8, h = i & 255;
    int id = step * 6 + 3 + c;  // dir = 1
    s_cp[c][h] = ws[WS_CP + id * 256 + h];
    s_dinv[c][h] = ws[WS_DINV + id * 256 + h];
  }
  if (tid < 3) {
    s_r[tid] = ws[WS_R + step * 6 + 3 + tid];
    s_diag[tid] = coupling[tid * 3 + tid];
  }
  __syncthreads();

  int g = blockIdx.x * 256 + tid;          // (b*C + c)*256 + w
  int c = (g >> 8) % 3;
  float r = s_r[c];
  float diag = s_diag[c];
  const float* cp = s_cp[c];
  const float* dinv = s_dinv[c];
  float* p = buf + (size_t)(g >> 8) * HWn + (g & 255);

  // forward: dp (stored in place)
  float prev = p[0] * dinv[0];
  p[0] = prev;
  for (int h = 1; h < 256; ++h) {
    float v = p[(size_t)h * 256];
    prev = (v + r * prev) * dinv[h];
    p[(size_t)h * 256] = prev;
  }
  // backward: x, scaled by diag on write
  float x = prev;  // dp[255]
  p[(size_t)255 * 256] = x * diag;
  for (int h = 254; h >= 0; --h) {
    float dpv = p[(size_t)h * 256];
    x = dpv - cp[h] * x;
    p[(size_t)h * 256] = x * diag;
  }
}

extern "C" void kernel_launch(void* const* d_in, const int* in_sizes, int n_in,
                              void* d_out, int out_size, void* d_ws, size_t ws_size,
                              hipStream_t stream) {
  const float* u = (const float*)d_in[0];
  const float* alpha_base = (const float*)d_in[1];
  const float* beta_base = (const float*)d_in[2];
  const float* alpha_spatial = (const float*)d_in[3];
  const float* beta_spatial = (const float*)d_in[4];
  const float* coupling = (const float*)d_in[5];
  float* out = (float*)d_out;
  float* ws = (float*)d_ws;

  means_kernel<<<6, 256, 0, stream>>>(alpha_spatial, beta_spatial, ws);
  coeff_kernel<<<1, 64, 0, stream>>>(alpha_base, beta_base, ws);

  for (int step = 0; step < 3; ++step) {
    const float* src = (step == 0) ? u : out;
    sweep_x<<<NSYS / 256, 256, 0, stream>>>(src, out, ws, step);
    sweep_y<<<NSYS / 256, 256, 0, stream>>>(out, ws, coupling, step);
  }
}

// Round 2
// 359.676 us; speedup vs baseline: 1.7710x; 1.7710x over previous
//
#include <hip/hip_runtime.h>

// Problem constants (fixed by setup_inputs)
constexpr int Bn = 128, Cn = 3, Sn = 256;
constexpr int HWn = Sn * Sn;          // 65536
constexpr int NSYS = Bn * Cn * Sn;    // 98304 systems per sweep
constexpr float DTf = 0.05f;
constexpr float EPSf = 1e-6f;
constexpr float MAXCf = 1.0f;

// ws float layout:
//   [0..5]                 spatial means: alpha(3), beta(3)
//   [8..25]                r[step][dir][c]  (18)
//   [32 .. 32+4608)        cp tables   [18][256]   (cp[255] = true value)
//   [4640 .. 4640+4608)    dinv tables [18][256]
#define WS_R    8
#define WS_CP   32
#define WS_DINV 4640

__global__ void means_kernel(const float* __restrict__ aspat,
                             const float* __restrict__ bspat,
                             float* __restrict__ ws) {
  int which = blockIdx.x / 3, c = blockIdx.x % 3;
  const float4* src = (const float4*)((which == 0 ? aspat : bspat) + c * HWn);
  double acc = 0.0;
  for (int i = threadIdx.x; i < HWn / 4; i += 256) {
    float4 v = src[i];
    acc += (double)v.x + (double)v.y + (double)v.z + (double)v.w;
  }
  __shared__ double sm[256];
  sm[threadIdx.x] = acc;
  __syncthreads();
  for (int s = 128; s > 0; s >>= 1) {
    if (threadIdx.x < s) sm[threadIdx.x] += sm[threadIdx.x + s];
    __syncthreads();
  }
  if (threadIdx.x == 0) ws[which * 3 + c] = (float)(sm[0] * (1.0 / HWn));
}

// One thread per (step, dir, channel): build cp[256], dinv[256], r.
__global__ void coeff_kernel(const float* __restrict__ alpha_base,
                             const float* __restrict__ beta_base,
                             float* __restrict__ ws) {
  int id = threadIdx.x;
  if (id >= 18) return;
  int s = id / 6, dir = (id / 3) % 2, c = id % 3;
  float t = (float)s * DTf;
  float mean = ws[dir * 3 + c];
  float base = (dir == 0) ? alpha_base[c] : beta_base[c];
  float coef = fminf(fmaxf(base + mean * t, EPSf), MAXCf);
  float r = coef * (DTf * 0.5f);  // DX = 1
  ws[WS_R + id] = r;
  float* cp = ws + WS_CP + id * 256;
  float* dinv = ws + WS_DINV + id * 256;
  float b0 = 1.0f + r;
  float bi = 1.0f + 2.0f * r;
  dinv[0] = 1.0f / (b0 + EPSf);
  cp[0] = -r / (b0 + EPSf);
  for (int i = 1; i < 256; ++i) {
    float b = (i == 255) ? b0 : bi;
    float denom = fmaxf(b + r * cp[i - 1], EPSf);  // b - a*cp_prev, a=-r
    cp[i] = -r / denom;
    dinv[i] = 1.0f / denom;
  }
  // NOTE: cp[255] kept at its true value (-r/denom) — sweep_x forward uses
  // -cp[w] == r*dinv[w] at ALL w; back-substitution starts at w=255 explicitly.
}

// X sweep: systems along W (contiguous). One wave (64 threads) per block,
// 64 rows staged in LDS. Layout: element (row,col) at word 256*row + (col ^ (row&28)).
//  - staging: global_load_lds 16B/lane, LINEAR lds dest, pre-swizzled global src
//  - solve:   thread-per-row ds_read_b128/ds_write_b128, group-XOR avoids the
//             64-lane same-bank-group column conflict (capacity-bound instead)
//  - store:   linear LDS read, swizzled coalesced float4 global store
__global__ __launch_bounds__(64) void sweep_x(const float* src, float* dst,
                                              const float* __restrict__ ws, int step) {
  __shared__ float tile[64 * 256];   // 64 KiB
  __shared__ float s_dinv[256];
  __shared__ float s_cp[256];
  const int l = threadIdx.x;
  const int g0 = blockIdx.x * 64;          // first system of this block
  const int c = (g0 >> 8) % 3;             // 64 | 256 -> whole block same channel
  const int id = step * 6 + c;             // dir = 0

  // coefficient tables -> LDS (float4 per lane x 1)
  ((float4*)s_dinv)[l] = ((const float4*)(ws + WS_DINV + id * 256))[l];
  ((float4*)s_cp)[l]   = ((const float4*)(ws + WS_CP + id * 256))[l];
  const float r = ws[WS_R + id];

  // stage 64 rows: one DMA per row (64 lanes x 16B = the whole row)
  const float* srcb = src + (size_t)g0 * 256;
#pragma unroll
  for (int i = 0; i < 64; ++i) {
    const float* gp = srcb + i * 256 + ((4 * l) ^ (i & 28));
    __builtin_amdgcn_global_load_lds(
        (const __attribute__((address_space(1))) void*)gp,
        (__attribute__((address_space(3))) void*)(tile + i * 256), 16, 0, 0);
  }
  asm volatile("s_waitcnt vmcnt(0)" ::: "memory");
  __syncthreads();

  const int sw = (l >> 2) & 7;             // group-level swizzle for this row
  float4* trow = (float4*)tile + l * 64;
  const float4* di4 = (const float4*)s_dinv;
  const float4* cp4 = (const float4*)s_cp;

  // forward: dp[w] = v*dinv[w] + (r*dinv[w])*prev = fma(-cp[w], prev, v*dinv[w])
  float prev = 0.0f;                        // cp[0]*0 contributes nothing at w=0
#pragma unroll 8
  for (int w4 = 0; w4 < 64; ++w4) {
    int g = w4 ^ sw;
    float4 v = trow[g];
    float4 di = di4[w4];
    float4 cq = cp4[w4];
    float d0 = fmaf(-cq.x, prev, v.x * di.x);
    float d1 = fmaf(-cq.y, d0,   v.y * di.y);
    float d2 = fmaf(-cq.z, d1,   v.z * di.z);
    float d3 = fmaf(-cq.w, d2,   v.w * di.w);
    trow[g] = make_float4(d0, d1, d2, d3);
    prev = d3;
  }
  // backward: x[w] = dp[w] - cp[w]*x[w+1]; x[255] = dp[255]
  float x;
  {
    int g = 63 ^ sw;
    float4 v = trow[g];
    float4 cq = cp4[63];
    float x3 = v.w;
    float x2 = fmaf(-cq.z, x3, v.z);
    float x1 = fmaf(-cq.y, x2, v.y);
    float x0 = fmaf(-cq.x, x1, v.x);
    trow[g] = make_float4(x0, x1, x2, x3);
    x = x0;
  }
#pragma unroll 8
  for (int w4 = 62; w4 >= 0; --w4) {
    int g = w4 ^ sw;
    float4 v = trow[g];
    float4 cq = cp4[w4];
    float x3 = fmaf(-cq.w, x, v.w);
    float x2 = fmaf(-cq.z, x3, v.z);
    float x1 = fmaf(-cq.y, x2, v.y);
    float x0 = fmaf(-cq.x, x1, v.x);
    trow[g] = make_float4(x0, x1, x2, x3);
    x = x0;
  }
  __syncthreads();

  // store: linear LDS read (lane l -> words 4l..4l+3 of row i, holding cols
  // (4l^(i&28))..+3 in order) -> coalesced float4 global store
  float* dstb = dst + (size_t)g0 * 256;
#pragma unroll 8
  for (int i = 0; i < 64; ++i) {
    float4 v = *(const float4*)(tile + i * 256 + 4 * l);
    *(float4*)(dstb + i * 256 + ((4 * l) ^ (i & 28))) = v;
  }
  (void)r;
}

// Y sweep: systems along H (stride 256). One thread per (b,c,w) — coalesced.
// In place on buf; final write scaled by diag(coupling)[c].
__global__ void sweep_y(float* buf, const float* __restrict__ ws,
                        const float* __restrict__ coupling, int step) {
  __shared__ float s_cp[3][256], s_dinv[3][256], s_r[3], s_diag[3];
  int tid = threadIdx.x;
  for (int i = tid; i < 3 * 256; i += 256) {
    int c = i >> 8, h = i & 255;
    int id = step * 6 + 3 + c;  // dir = 1
    s_cp[c][h] = ws[WS_CP + id * 256 + h];
    s_dinv[c][h] = ws[WS_DINV + id * 256 + h];
  }
  if (tid < 3) {
    s_r[tid] = ws[WS_R + step * 6 + 3 + tid];
    s_diag[tid] = coupling[tid * 3 + tid];
  }
  __syncthreads();

  int g = blockIdx.x * 256 + tid;          // (b*C + c)*256 + w
  int c = (g >> 8) % 3;
  float r = s_r[c];
  float diag = s_diag[c];
  const float* cp = s_cp[c];
  const float* dinv = s_dinv[c];
  float* p = buf + (size_t)(g >> 8) * HWn + (g & 255);

  // forward: dp (stored in place)
  float prev = p[0] * dinv[0];
  p[0] = prev;
  for (int h = 1; h < 256; ++h) {
    float v = p[(size_t)h * 256];
    prev = (v + r * prev) * dinv[h];
    p[(size_t)h * 256] = prev;
  }
  // backward: x, scaled by diag on write (cp[255] not used)
  float x = prev;  // dp[255]
  p[(size_t)255 * 256] = x * diag;
  for (int h = 254; h >= 0; --h) {
    float dpv = p[(size_t)h * 256];
    x = dpv - cp[h] * x;
    p[(size_t)h * 256] = x * diag;
  }
}

extern "C" void kernel_launch(void* const* d_in, const int* in_sizes, int n_in,
                              void* d_out, int out_size, void* d_ws, size_t ws_size,
                              hipStream_t stream) {
  const float* u = (const float*)d_in[0];
  const float* alpha_base = (const float*)d_in[1];
  const float* beta_base = (const float*)d_in[2];
  const float* alpha_spatial = (const float*)d_in[3];
  const float* beta_spatial = (const float*)d_in[4];
  const float* coupling = (const float*)d_in[5];
  float* out = (float*)d_out;
  float* ws = (float*)d_ws;

  means_kernel<<<6, 256, 0, stream>>>(alpha_spatial, beta_spatial, ws);
  coeff_kernel<<<1, 64, 0, stream>>>(alpha_base, beta_base, ws);

  for (int step = 0; step < 3; ++step) {
    const float* src = (step == 0) ? u : out;
    sweep_x<<<NSYS / 64, 64, 0, stream>>>(src, out, ws, step);
    sweep_y<<<NSYS / 256, 256, 0, stream>>>(out, ws, coupling, step);
  }
}

// Round 3
// 165.119 us; speedup vs baseline: 3.8577x; 2.1783x over previous
//
#include <hip/hip_runtime.h>

// Problem constants (fixed by setup_inputs)
constexpr int Bn = 128, Cn = 3, Sn = 256;
constexpr int HWn = Sn * Sn;          // 65536
constexpr int NPLANE = Bn * Cn;       // 384
constexpr int NSYS = NPLANE * Sn;     // 98304 systems per sweep
constexpr float DTf = 0.05f;
constexpr float EPSf = 1e-6f;
constexpr float MAXCf = 1.0f;

// ws float layout:
//   [8..25]            r[step][dir][c]  (18)  (fallback sweep_y needs r)
//   [32..127]          means partials (6 groups x 16 blocks)
//   [128..4735]        cp tables   [18][256]  (cp[255] = TRUE value)
//   [4736..9343]       dinv tables [18][256]
//   [16384..]          ping-pong buffer (25165824 floats) when ws_size permits
#define WS_R    8
#define WS_PART 32
#define WS_CP   128
#define WS_DINV 4736
#define WS_BUF  16384

__global__ void means_part(const float* __restrict__ aspat,
                           const float* __restrict__ bspat,
                           float* __restrict__ ws) {
  int grp = blockIdx.x >> 4;   // 0..5 = dir*3 + c
  int sub = blockIdx.x & 15;
  const float* base = (grp < 3) ? (aspat + grp * HWn) : (bspat + (grp - 3) * HWn);
  const float4* p = (const float4*)base + sub * 1024 + threadIdx.x;
  double acc = 0.0;
#pragma unroll
  for (int k = 0; k < 4; ++k) {
    float4 v = p[k * 256];
    acc += (double)v.x + (double)v.y + (double)v.z + (double)v.w;
  }
  __shared__ double sm[256];
  sm[threadIdx.x] = acc;
  __syncthreads();
  for (int s = 128; s > 0; s >>= 1) {
    if (threadIdx.x < s) sm[threadIdx.x] += sm[threadIdx.x + s];
    __syncthreads();
  }
  if (threadIdx.x == 0) ws[WS_PART + blockIdx.x] = (float)sm[0];
}

// One thread per (step, dir, channel): build cp[256], dinv[256], r.
__global__ void coeff_kernel(const float* __restrict__ alpha_base,
                             const float* __restrict__ beta_base,
                             float* __restrict__ ws) {
  int id = threadIdx.x;
  if (id >= 18) return;
  int s = id / 6, dir = (id / 3) % 2, c = id % 3;
  double msum = 0.0;
  for (int k = 0; k < 16; ++k) msum += (double)ws[WS_PART + (dir * 3 + c) * 16 + k];
  float mean = (float)(msum * (1.0 / HWn));
  float t = (float)s * DTf;
  float base = (dir == 0) ? alpha_base[c] : beta_base[c];
  float coef = fminf(fmaxf(base + mean * t, EPSf), MAXCf);
  float r = coef * (DTf * 0.5f);  // DX = 1
  ws[WS_R + id] = r;
  float* cp = ws + WS_CP + id * 256;
  float* dinv = ws + WS_DINV + id * 256;
  float b0 = 1.0f + r;
  float bi = 1.0f + 2.0f * r;
  dinv[0] = 1.0f / (b0 + EPSf);
  cp[0] = -r / (b0 + EPSf);
  for (int i = 1; i < 256; ++i) {
    float b = (i == 255) ? b0 : bi;
    float denom = fmaxf(b + r * cp[i - 1], EPSf);  // b - a*cp_prev, a=-r
    cp[i] = -r / denom;
    dinv[i] = 1.0f / denom;
  }
  // cp[255] kept TRUE: forward uses -cp[i]==r*dinv[i] at all i; back-subst
  // never multiplies cp[255] (starts x_255 = dp_255 explicitly).
}

// ---------------- Fused per-step kernel (x-solve + y-solve) ----------------
// Halo-truncation: influence decays as (r*dinv)^k ~ 0.0075^k, so an 8-elem
// halo makes chunk solves bit-near-identical to the full Thomas solve.
// Block = one 64-row x 256-col window of one (b,c) plane.
// Stripes (5 per plane): window rows w0=s*48, core rows {[0,56),[8,56)x3,[8,64)}.
// LDS tile swizzle: element (row,col) lives at word row*256 + ((col>>2)^(row&7))*4 + (col&3).
__global__ __launch_bounds__(256, 2) void fused_step(
    const float* __restrict__ src, float* __restrict__ dst,
    const float* __restrict__ ws, const float* __restrict__ coupling, int step) {
  __shared__ float tile[64 * 256];       // 64 KiB
  __shared__ float s_cpx[256], s_dix[256], s_cpy[256], s_diy[256];
  __shared__ float s_diag;

  const int t = threadIdx.x;
  const int bid = blockIdx.x;
  const int plane = bid / 5;            // b*3 + c
  const int s = bid % 5;                // stripe
  const int c = plane % 3;
  const int idx_ = step * 6 + c;        // x-dir tables
  const int idy_ = idx_ + 3;            // y-dir tables

  s_cpx[t] = ws[WS_CP + idx_ * 256 + t];
  s_dix[t] = ws[WS_DINV + idx_ * 256 + t];
  s_cpy[t] = ws[WS_CP + idy_ * 256 + t];
  s_diy[t] = ws[WS_DINV + idy_ * 256 + t];
  if (t == 0) s_diag = coupling[c * 3 + c];

  const int w0 = s * 48;                          // window start row
  const int coreLo = (s == 0) ? 0 : 8;            // window-relative
  const int coreHi = (s == 4) ? 64 : 56;

  // Phase A: DMA 64 window rows into LDS. Lane l of a wave writes LDS words
  // r*256+4l (linear dest); source col-quad = l ^ (r&7) (inverse swizzle).
  const float* srcp = src + (size_t)plane * HWn;
  const int wv = t >> 6, l = t & 63;
#pragma unroll
  for (int k = 0; k < 16; ++k) {
    int r = wv * 16 + k;
    const float* gp = srcp + (size_t)(w0 + r) * 256 + ((l ^ (r & 7)) << 2);
    __builtin_amdgcn_global_load_lds(
        (const __attribute__((address_space(1))) void*)gp,
        (__attribute__((address_space(3))) void*)(tile + r * 256), 16, 0, 0);
  }
  asm volatile("s_waitcnt vmcnt(0)" ::: "memory");
  __syncthreads();

  // Phase B: x-solve. Thread t -> window row rw = t>>2, col-chunk cw = t&3.
  // Chunk col-windows (quads): {[0,20),[14,34),[30,50),[44,64)}; core quads
  // [16cw,16cw+16). Halo reads overlap only within the same 4-lane group
  // (same wave -> lockstep: all fwd reads precede any bwd write). In-LDS
  // in-place: each thread writes only its own core quads.
  {
    const int rw = t >> 2, cw = t & 3;
    const int s0q = (cw == 0) ? 0 : (cw == 1) ? 14 : (cw == 2) ? 30 : 44;
    const int rqlo = 16 * cw - s0q;               // {0,2,2,4}
    const int sw = rw & 7;
    float4* t4 = (float4*)tile + rw * 64;
    const float4* cpx4 = (const float4*)s_cpx;
    const float4* dix4 = (const float4*)s_dix;
    float4 dq[20];
    float prev = 0.0f;                            // halo-truncated start
#pragma unroll
    for (int q = 0; q < 20; ++q) {
      float4 v = t4[(s0q + q) ^ sw];
      float4 cq = cpx4[s0q + q];
      float4 eq = dix4[s0q + q];
      float d0 = fmaf(-cq.x, prev, v.x * eq.x);
      float d1 = fmaf(-cq.y, d0, v.y * eq.y);
      float d2 = fmaf(-cq.z, d1, v.z * eq.z);
      float d3 = fmaf(-cq.w, d2, v.w * eq.w);
      dq[q] = make_float4(d0, d1, d2, d3);
      prev = d3;
    }
    float x;
    {
      float4 v = dq[19];
      float4 cq = cpx4[s0q + 19];
      float x3 = v.w;                             // truncated top (exact for cw3)
      float x2 = fmaf(-cq.z, x3, v.z);
      float x1 = fmaf(-cq.y, x2, v.y);
      float x0 = fmaf(-cq.x, x1, v.x);
      if (19 >= rqlo && 19 < rqlo + 16) t4[(s0q + 19) ^ sw] = make_float4(x0, x1, x2, x3);
      x = x0;
    }
#pragma unroll
    for (int q = 18; q >= 0; --q) {
      float4 v = dq[q];
      float4 cq = cpx4[s0q + q];
      float x3 = fmaf(-cq.w, x, v.w);
      float x2 = fmaf(-cq.z, x3, v.z);
      float x1 = fmaf(-cq.y, x2, v.y);
      float x0 = fmaf(-cq.x, x1, v.x);
      if (q >= rqlo && q < rqlo + 16) t4[(s0q + q) ^ sw] = make_float4(x0, x1, x2, x3);
      x = x0;
    }
  }
  __syncthreads();

  // Phase C: y-solve, thread-per-column j = t over the 64 window rows with
  // TRUE global-row tables; store core rows scaled by diag, coalesced.
  {
    const int j = t;
    const int jq = j >> 2, jr = j & 3;
    float dpy[64];
    float prev = 0.0f;                            // exact for s==0, halo else
#pragma unroll
    for (int h = 0; h < 64; ++h) {
      float v = tile[h * 256 + (((jq ^ (h & 7)) << 2) | jr)];
      int g = w0 + h;
      prev = fmaf(-s_cpy[g], prev, v * s_diy[g]);
      dpy[h] = prev;
    }
    const float diag = s_diag;
    float* dstp = dst + (size_t)plane * HWn + j;
    float x = dpy[63];                            // exact for s==4, halo else
    if (63 < coreHi) dstp[(size_t)(w0 + 63) * 256] = x * diag;
#pragma unroll
    for (int h = 62; h >= 0; --h) {
      int g = w0 + h;
      x = fmaf(-s_cpy[g], x, dpy[h]);
      if (h >= coreLo && h < coreHi) dstp[(size_t)g * 256] = x * diag;
    }
  }
}

// ---------------- Fallback path (round-2 kernels, in-place capable) --------
__global__ __launch_bounds__(64) void sweep_x(const float* src, float* dst,
                                              const float* __restrict__ ws, int step) {
  __shared__ float tile[64 * 256];
  __shared__ float s_dinv[256];
  __shared__ float s_cp[256];
  const int l = threadIdx.x;
  const int g0 = blockIdx.x * 64;
  const int c = (g0 >> 8) % 3;
  const int id = step * 6 + c;

  ((float4*)s_dinv)[l] = ((const float4*)(ws + WS_DINV + id * 256))[l];
  ((float4*)s_cp)[l] = ((const float4*)(ws + WS_CP + id * 256))[l];

  const float* srcb = src + (size_t)g0 * 256;
#pragma unroll
  for (int i = 0; i < 64; ++i) {
    const float* gp = srcb + i * 256 + ((4 * l) ^ (i & 28));
    __builtin_amdgcn_global_load_lds(
        (const __attribute__((address_space(1))) void*)gp,
        (__attribute__((address_space(3))) void*)(tile + i * 256), 16, 0, 0);
  }
  asm volatile("s_waitcnt vmcnt(0)" ::: "memory");
  __syncthreads();

  const int sw = (l >> 2) & 7;
  float4* trow = (float4*)tile + l * 64;
  const float4* di4 = (const float4*)s_dinv;
  const float4* cp4 = (const float4*)s_cp;

  float prev = 0.0f;
#pragma unroll 8
  for (int w4 = 0; w4 < 64; ++w4) {
    int g = w4 ^ sw;
    float4 v = trow[g];
    float4 di = di4[w4];
    float4 cq = cp4[w4];
    float d0 = fmaf(-cq.x, prev, v.x * di.x);
    float d1 = fmaf(-cq.y, d0, v.y * di.y);
    float d2 = fmaf(-cq.z, d1, v.z * di.z);
    float d3 = fmaf(-cq.w, d2, v.w * di.w);
    trow[g] = make_float4(d0, d1, d2, d3);
    prev = d3;
  }
  float x;
  {
    int g = 63 ^ sw;
    float4 v = trow[g];
    float4 cq = cp4[63];
    float x3 = v.w;
    float x2 = fmaf(-cq.z, x3, v.z);
    float x1 = fmaf(-cq.y, x2, v.y);
    float x0 = fmaf(-cq.x, x1, v.x);
    trow[g] = make_float4(x0, x1, x2, x3);
    x = x0;
  }
#pragma unroll 8
  for (int w4 = 62; w4 >= 0; --w4) {
    int g = w4 ^ sw;
    float4 v = trow[g];
    float4 cq = cp4[w4];
    float x3 = fmaf(-cq.w, x, v.w);
    float x2 = fmaf(-cq.z, x3, v.z);
    float x1 = fmaf(-cq.y, x2, v.y);
    float x0 = fmaf(-cq.x, x1, v.x);
    trow[g] = make_float4(x0, x1, x2, x3);
    x = x0;
  }
  __syncthreads();

  float* dstb = dst + (size_t)g0 * 256;
#pragma unroll 8
  for (int i = 0; i < 64; ++i) {
    float4 v = *(const float4*)(tile + i * 256 + 4 * l);
    *(float4*)(dstb + i * 256 + ((4 * l) ^ (i & 28))) = v;
  }
}

__global__ void sweep_y(float* buf, const float* __restrict__ ws,
                        const float* __restrict__ coupling, int step) {
  __shared__ float s_cp[3][256], s_dinv[3][256], s_r[3], s_diag[3];
  int tid = threadIdx.x;
  for (int i = tid; i < 3 * 256; i += 256) {
    int c = i >> 8, h = i & 255;
    int id = step * 6 + 3 + c;
    s_cp[c][h] = ws[WS_CP + id * 256 + h];
    s_dinv[c][h] = ws[WS_DINV + id * 256 + h];
  }
  if (tid < 3) {
    s_r[tid] = ws[WS_R + step * 6 + 3 + tid];
    s_diag[tid] = coupling[tid * 3 + tid];
  }
  __syncthreads();

  int g = blockIdx.x * 256 + tid;
  int c = (g >> 8) % 3;
  float r = s_r[c];
  float diag = s_diag[c];
  const float* cp = s_cp[c];
  const float* dinv = s_dinv[c];
  float* p = buf + (size_t)(g >> 8) * HWn + (g & 255);

  float prev = p[0] * dinv[0];
  p[0] = prev;
  for (int h = 1; h < 256; ++h) {
    float v = p[(size_t)h * 256];
    prev = (v + r * prev) * dinv[h];
    p[(size_t)h * 256] = prev;
  }
  float x = prev;
  p[(size_t)255 * 256] = x * diag;
  for (int h = 254; h >= 0; --h) {
    float dpv = p[(size_t)h * 256];
    x = dpv - cp[h] * x;
    p[(size_t)h * 256] = x * diag;
  }
}

extern "C" void kernel_launch(void* const* d_in, const int* in_sizes, int n_in,
                              void* d_out, int out_size, void* d_ws, size_t ws_size,
                              hipStream_t stream) {
  const float* u = (const float*)d_in[0];
  const float* alpha_base = (const float*)d_in[1];
  const float* beta_base = (const float*)d_in[2];
  const float* alpha_spatial = (const float*)d_in[3];
  const float* beta_spatial = (const float*)d_in[4];
  const float* coupling = (const float*)d_in[5];
  float* out = (float*)d_out;
  float* ws = (float*)d_ws;

  means_part<<<96, 256, 0, stream>>>(alpha_spatial, beta_spatial, ws);
  coeff_kernel<<<1, 64, 0, stream>>>(alpha_base, beta_base, ws);

  const size_t need = (size_t)(WS_BUF + (size_t)NPLANE * HWn) * sizeof(float);
  if (ws_size >= need) {
    float* buf = ws + WS_BUF;
    // u -> out -> buf -> out  (fused x+y per step; src != dst required)
    fused_step<<<NPLANE * 5, 256, 0, stream>>>(u, out, ws, coupling, 0);
    fused_step<<<NPLANE * 5, 256, 0, stream>>>(out, buf, ws, coupling, 1);
    fused_step<<<NPLANE * 5, 256, 0, stream>>>(buf, out, ws, coupling, 2);
  } else {
    for (int step = 0; step < 3; ++step) {
      const float* src = (step == 0) ? u : out;
      sweep_x<<<NSYS / 64, 64, 0, stream>>>(src, out, ws, step);
      sweep_y<<<NSYS / 256, 256, 0, stream>>>(out, ws, coupling, step);
    }
  }
}